// Round 13
// baseline (20511.388 us; speedup 1.0000x reference)
//
#include <hip/hip_runtime.h>

#define T_STEPS  8192
#define INPUT_N  256
#define OUTPUT_N 256
#define RES_N    4096
#define NB       256   // blocks (1 per CU)
#define NT       1024  // threads per block (16 waves)
#define RPB      16    // rows per block

#define PIN(x) asm volatile("" : "+v"(x))
#define PINU4(v) do { PIN((v).x); PIN((v).y); PIN((v).z); PIN((v).w); } while (0)

typedef unsigned long long ull;
typedef _Float16 half2v __attribute__((ext_vector_type(2)));

// f32x2 -> packed f16x2 (v_cvt_pkrtz_f16_f32), as raw dword.
__device__ __forceinline__ unsigned pkf16(float lo, float hi) {
    return __builtin_bit_cast(unsigned, __builtin_amdgcn_cvt_pkrtz(lo, hi));
}
// acc += dot(f16x2 w, f16x2 s)  (v_dot2_f32_f16, f32 accumulate)
__device__ __forceinline__ float fdot2(unsigned w, unsigned s, float acc) {
    return __builtin_amdgcn_fdot2(__builtin_bit_cast(half2v, w),
                                  __builtin_bit_cast(half2v, s), acc, false);
}
// tanh via native exp + fast div: 1 - 2/(e^{2x}+1). |err| ~1e-6.
__device__ __forceinline__ float fast_tanh(float x) {
    const float e = __expf(2.0f * x);
    return 1.0f - __fdividef(2.0f, e + 1.0f);
}

// Persistent ESN: f16 LDS weights + dot2 MAC + self-flagging state exchange.
// R13 = R12 + ROTATING publisher/out-writer waves + poll-loads-first issue
// order.
//
// R12 lesson kept: publish must be ONE coalesced 64B wave-store (R11's
// distributed publish: WRITE_SIZE x5.7, -20%). New: the publish tail
// (~250-400cy combine+tanh+store after the barrier) was pinned to wave 15
// every step -> permanently on the critical path. Rotating pub = t&15
// spreads it: each wave absorbs one tail per 16 steps. Parity safety is
// unchanged by rotation (publisher-of-t reads lds_part[par] after barrier
// t; same-parity overwrite at t+2 is gated by barrier t+1, which the
// publisher reaches only after its read).
//
// Poll-first issue: in steady state the producer published during our MAC,
// so discovery = first-poll load latency. Issue the 2 b64 poll loads
// BEFORE the 8 ds_read weight prefetch (vmcnt vs lgkmcnt, independent),
// and check the first result without sleeping.
__global__ __launch_bounds__(NT)
void esn_persistent(
    const float* __restrict__ X,       // [T, 256]
    const float* __restrict__ state0,  // [4096]
    const float* __restrict__ W_in,    // [4096, 256]
    const float* __restrict__ W_res,   // [4096, 4096]
    const float* __restrict__ W_out,   // [256, 4096]
    float* __restrict__ out,           // [T, 256]
    unsigned* __restrict__ stbuf)      // ws: [2][4096] tagged, zeroed per call
{
    const int tid  = threadIdx.x;
    const int bid  = blockIdx.x;
    const int wid  = tid >> 6;
    const int lane = tid & 63;
    const int qg   = lane >> 2;
    const int rg   = lane & 3;
    const int cg   = wid * 16 + qg;

    __shared__ unsigned w_lds[2 * 16 * 4 * 64 * 4];  // 128 KB f16x2 weights
    __shared__ float lds_part[2][16][20];            // [par][row][wid], pad 20
    __shared__ float lds_pp[2][16];

    // ---- one-time: weights -> f16 pairs in LDS / registers ----
    float win[4];
#pragma unroll
    for (int r = 0; r < 4; ++r) {
        const int grow = bid * RPB + 4 * rg + r;
#pragma unroll
        for (int c = 0; c < 2; ++c) {
            const float* wr = W_res + (size_t)grow * RES_N + c * 2048 + 8 * cg;
            const float4 a = *(const float4*)wr;
            const float4 b = *(const float4*)(wr + 4);
            uint4 pk;
            pk.x = pkf16(a.x, a.y);
            pk.y = pkf16(a.z, a.w);
            pk.z = pkf16(b.x, b.y);
            pk.w = pkf16(b.z, b.w);
            ((uint4*)w_lds)[((c * 16 + wid) * 4 + r) * 64 + lane] = pk;
        }
        win[r] = W_in[(size_t)grow * INPUT_N + cg];
        PIN(win[r]);
    }
    unsigned wo[8];
#pragma unroll
    for (int m = 0; m < 8; ++m) {
        const int col = (m < 4) ? (8 * cg + 2 * m) : (2048 + 8 * cg + 2 * (m - 4));
        wo[m] = pkf16(W_out[(size_t)bid * RES_N + col],
                      W_out[(size_t)bid * RES_N + col + 1]);
        PIN(wo[m]);
    }

    // This lane's quarter-slice offset (4 consecutive state cols).
    const int ofs_base = ((rg < 2) ? (8 * cg) : (2048 + 8 * cg)) + 4 * (rg & 1);

    float xv = X[cg];  // x_0[cg]

#pragma unroll 1
    for (int t = 0; t <= T_STEPS; ++t) {
        const int par  = t & 1;
        const int ppar = (t + 1) & 1;
        const int pub  = t & 15;             // rotating publisher wave
        const int owr  = (t + 8) & 15;       // rotating out-writer wave

        // ---- issue poll loads FIRST (steady state: they already hit) ----
        const ull* sp = (const ull*)(stbuf + (size_t)ppar * RES_N + ofs_base);
        ull lo = 0, hi = 0;
        if (t > 0) {
            lo = __hip_atomic_load(sp, __ATOMIC_RELAXED, __HIP_MEMORY_SCOPE_AGENT);
            hi = __hip_atomic_load(sp + 1, __ATOMIC_RELAXED, __HIP_MEMORY_SCOPE_AGENT);
        }

        // ---- weight prefetch: ds_reads issue under the poll loads ----
        uint4 w[2][4];
#pragma unroll
        for (int c = 0; c < 2; ++c)
#pragma unroll
            for (int r = 0; r < 4; ++r) {
                w[c][r] = ((const uint4*)w_lds)[(((c * 16 + wid) * 4 + r) * 64) + lane];
                PINU4(w[c][r]);
            }

        // ---- acquire 4 tagged dwords of state_{t-1} ----
        unsigned d0, d1, d2, d3;
        if (t == 0) {
            const float4 q = *(const float4*)(state0 + ofs_base);
            d0 = pkf16(q.x, 0.f);
            d1 = pkf16(q.y, 0.f);
            d2 = pkf16(q.z, 0.f);
            d3 = pkf16(q.w, 0.f);
        } else {
            const unsigned exp = (unsigned)t;  // state_{t-1} tagged t
            for (;;) {
                d0 = (unsigned)lo; d1 = (unsigned)(lo >> 32);
                d2 = (unsigned)hi; d3 = (unsigned)(hi >> 32);
                const unsigned tmin =
                    min(min(d0 >> 16, d1 >> 16), min(d2 >> 16, d3 >> 16));
                if (tmin >= exp) break;
                __builtin_amdgcn_s_sleep(1);  // decongest L3 poll traffic
                lo = __hip_atomic_load(sp, __ATOMIC_RELAXED, __HIP_MEMORY_SCOPE_AGENT);
                hi = __hip_atomic_load(sp + 1, __ATOMIC_RELAXED, __HIP_MEMORY_SCOPE_AGENT);
            }
        }

        // prefetch next x (hidden under shuffles/MAC)
        const float xn = X[(size_t)((t + 1 < T_STEPS) ? (t + 1) : 0) * INPUT_N + cg];

        // ---- strip tags into f16x2 pairs, broadcast across the quad ----
        const unsigned pl0 = __builtin_amdgcn_perm(d1, d0, 0x05040100u);
        const unsigned pl1 = __builtin_amdgcn_perm(d3, d2, 0x05040100u);
        unsigned sp16[8];
#pragma unroll
        for (int m = 0; m < 8; ++m)
            sp16[m] = __shfl((m & 1) ? pl1 : pl0, (lane & 0x3C) | (m >> 1), 64);

        // ---- MAC: 4 rows x 8 dot2 on prefetched weights ----
        if (t < T_STEPS) {
            float p0 = win[0] * xv, p1 = win[1] * xv;
            float p2 = win[2] * xv, p3 = win[3] * xv;
#pragma unroll
            for (int c = 0; c < 2; ++c) {
                const unsigned s0 = sp16[4 * c + 0], s1 = sp16[4 * c + 1];
                const unsigned s2 = sp16[4 * c + 2], s3 = sp16[4 * c + 3];
                p0 = fdot2(w[c][0].x, s0, p0); p0 = fdot2(w[c][0].y, s1, p0);
                p0 = fdot2(w[c][0].z, s2, p0); p0 = fdot2(w[c][0].w, s3, p0);
                p1 = fdot2(w[c][1].x, s0, p1); p1 = fdot2(w[c][1].y, s1, p1);
                p1 = fdot2(w[c][1].z, s2, p1); p1 = fdot2(w[c][1].w, s3, p1);
                p2 = fdot2(w[c][2].x, s0, p2); p2 = fdot2(w[c][2].y, s1, p2);
                p2 = fdot2(w[c][2].z, s2, p2); p2 = fdot2(w[c][2].w, s3, p2);
                p3 = fdot2(w[c][3].x, s0, p3); p3 = fdot2(w[c][3].y, s1, p3);
                p3 = fdot2(w[c][3].z, s2, p3); p3 = fdot2(w[c][3].w, s3, p3);
            }
            // merged reduce over the 16 same-rg lanes (stride-4)
            p0 += __shfl_xor(p0, 4, 64); p1 += __shfl_xor(p1, 4, 64);
            p2 += __shfl_xor(p2, 4, 64); p3 += __shfl_xor(p3, 4, 64);
            p0 += __shfl_xor(p0, 8, 64); p1 += __shfl_xor(p1, 8, 64);
            p2 += __shfl_xor(p2, 8, 64); p3 += __shfl_xor(p3, 8, 64);
            float v = (qg & 1) ? ((qg & 2) ? p3 : p1)
                               : ((qg & 2) ? p2 : p0);
            v += __shfl_xor(v, 16, 64);
            v += __shfl_xor(v, 32, 64);
            if (lane < 16)
                lds_part[par][4 * (lane & 3) + (lane >> 2)][wid] = v;  // [row][w]
        }
        __syncthreads();  // the only per-step barrier

        // ---- publisher wave: b128 combine + fast_tanh + coalesced publish ----
        if (t < T_STEPS && wid == pub && lane < 16) {
            const float4 a = *(const float4*)(&lds_part[par][lane][0]);
            const float4 b = *(const float4*)(&lds_part[par][lane][4]);
            const float4 c = *(const float4*)(&lds_part[par][lane][8]);
            const float4 d = *(const float4*)(&lds_part[par][lane][12]);
            const float s = ((a.x + a.y) + (a.z + a.w)) + ((b.x + b.y) + (b.z + b.w))
                          + ((c.x + c.y) + (c.z + c.w)) + ((d.x + d.y) + (d.z + d.w));
            const float ns = fast_tanh(s);
            const unsigned dw = pkf16(ns, 0.f) | ((unsigned)(t + 1) << 16);
            // 16 lanes, consecutive dwords: one 64B store -> atomic visibility
            __hip_atomic_store(stbuf + (size_t)par * RES_N + bid * RPB + lane,
                               dw, __ATOMIC_RELAXED, __HIP_MEMORY_SCOPE_AGENT);
        }

        // ---- out-writer wave: delayed pred reduce -> out[t-2] ----
        if (t >= 2 && wid == owr && lane < 16) {
            float pv = lds_pp[ppar][lane];
            pv += __shfl_xor(pv, 8, 64);
            pv += __shfl_xor(pv, 4, 64);
            pv += __shfl_xor(pv, 2, 64);
            pv += __shfl_xor(pv, 1, 64);
            if (lane == 0) out[(size_t)(t - 2) * OUTPUT_N + bid] = pv;
        }

        // ---- pred partial for state_{t-1} (off critical path) ----
        if (t > 0) {
            float pp = 0.f;
            if (rg == 0) {
#pragma unroll
                for (int m = 0; m < 8; ++m) pp = fdot2(wo[m], sp16[m], pp);
            }
            pp += __shfl_xor(pp, 4, 64);
            pp += __shfl_xor(pp, 8, 64);
            pp += __shfl_xor(pp, 16, 64);
            pp += __shfl_xor(pp, 32, 64);
            if (lane == 0) lds_pp[par][wid] = pp;
        }

        xv = xn;
    }

    // ---- epilogue: out[T-1] from iteration T's pred partials ----
    __syncthreads();
    if (wid == 0 && lane < 16) {
        float pv = lds_pp[T_STEPS & 1][lane];
        pv += __shfl_xor(pv, 8, 64);
        pv += __shfl_xor(pv, 4, 64);
        pv += __shfl_xor(pv, 2, 64);
        pv += __shfl_xor(pv, 1, 64);
        if (lane == 0) out[(size_t)(T_STEPS - 1) * OUTPUT_N + bid] = pv;
    }
}

extern "C" void kernel_launch(void* const* d_in, const int* in_sizes, int n_in,
                              void* d_out, int out_size, void* d_ws, size_t ws_size,
                              hipStream_t stream) {
    const float* X      = (const float*)d_in[0];
    const float* state0 = (const float*)d_in[1];
    const float* W_in   = (const float*)d_in[2];
    const float* W_res  = (const float*)d_in[3];
    const float* W_out  = (const float*)d_in[4];
    float* out = (float*)d_out;

    unsigned* stbuf = (unsigned*)d_ws;  // 2*4096 tagged dwords = 32 KiB

    // Tags must start below any expected value every call (graph replays
    // reuse d_ws without re-poisoning; stale tags would satisfy the spin).
    (void)hipMemsetAsync(stbuf, 0, 2 * RES_N * sizeof(unsigned), stream);

    esn_persistent<<<dim3(NB), dim3(NT), 0, stream>>>(
        X, state0, W_in, W_res, W_out, out, stbuf);
}

// Round 14
// 17574.403 us; speedup vs baseline: 1.1671x; 1.1671x over previous
//
#include <hip/hip_runtime.h>

#define T_STEPS  8192
#define INPUT_N  256
#define OUTPUT_N 256
#define RES_N    4096
#define NB       256   // blocks (1 per CU)
#define NT       1024  // threads per block (16 waves)
#define RPB      16    // rows per block

#define PIN(x) asm volatile("" : "+v"(x))
#define PINU4(v) do { PIN((v).x); PIN((v).y); PIN((v).z); PIN((v).w); } while (0)

typedef unsigned long long ull;
typedef _Float16 half2v __attribute__((ext_vector_type(2)));

// f32x2 -> packed f16x2 (v_cvt_pkrtz_f16_f32), as raw dword.
__device__ __forceinline__ unsigned pkf16(float lo, float hi) {
    return __builtin_bit_cast(unsigned, __builtin_amdgcn_cvt_pkrtz(lo, hi));
}
// acc += dot(f16x2 w, f16x2 s)  (v_dot2_f32_f16, f32 accumulate)
__device__ __forceinline__ float fdot2(unsigned w, unsigned s, float acc) {
    return __builtin_amdgcn_fdot2(__builtin_bit_cast(half2v, w),
                                  __builtin_bit_cast(half2v, s), acc, false);
}
// tanh via native exp + fast div: 1 - 2/(e^{2x}+1). |err| ~1e-6.
__device__ __forceinline__ float fast_tanh(float x) {
    const float e = __expf(2.0f * x);
    return 1.0f - __fdividef(2.0f, e + 1.0f);
}

// Persistent ESN: f16 LDS weights + dot2 MAC + self-flagging state exchange.
// EXACT R12 revert — best proven state (17.6 ms).
//
// Change ledger (exchange-touching changes: 4/4 regressed):
//   R11 distributed publish: WRITE x5.7, -20%  -> publish = ONE 64B wave-store
//   R13 rotating publisher:  +17% dur — the publish tail is on the BLOCK-level
//        critical path regardless of which wave issues it; rotation only adds
//        runtime-wid overhead. Fixed wave15 publisher it is.
//   R13 poll-first issue: more first-poll misses (FETCH +40%). Weight
//        prefetch BEFORE the spin (R12 order) is correct: ds_reads issue
//        under the spin latency on the lgkm counter.
//
// Exchange: stbuf[2][4096] dwords; dword i of parity p =
// f16(state[i]) | (t+1)<<16 — the tag IS the flag. Consumer lane spins on
// its own 4 data dwords (min tag >= t). Lap-proof by transitivity (every
// block consumes every block's slice every step). stbuf zeroed per call.
//
// Step (1 barrier): prefetch weights (ds_read issues under spin) -> spin
// (s_sleep backoff) -> tag-strip + quad-broadcast (8 f16x2) -> MAC (32
// dot2) + merged reduce -> lds_part[par][row][wid] (stride 20) ->
// syncthreads -> wave15: 4xb128 combine + fast_tanh + coalesced 64B
// tagged publish; wave14: reduce lds_pp[ppar] -> out[t-2]; all: pred
// partial -> lds_pp[par] (off critical path).
__global__ __launch_bounds__(NT)
void esn_persistent(
    const float* __restrict__ X,       // [T, 256]
    const float* __restrict__ state0,  // [4096]
    const float* __restrict__ W_in,    // [4096, 256]
    const float* __restrict__ W_res,   // [4096, 4096]
    const float* __restrict__ W_out,   // [256, 4096]
    float* __restrict__ out,           // [T, 256]
    unsigned* __restrict__ stbuf)      // ws: [2][4096] tagged, zeroed per call
{
    const int tid  = threadIdx.x;
    const int bid  = blockIdx.x;
    const int wid  = tid >> 6;
    const int lane = tid & 63;
    const int qg   = lane >> 2;
    const int rg   = lane & 3;
    const int cg   = wid * 16 + qg;

    __shared__ unsigned w_lds[2 * 16 * 4 * 64 * 4];  // 128 KB f16x2 weights
    __shared__ float lds_part[2][16][20];            // [par][row][wid], pad 20
    __shared__ float lds_pp[2][16];

    // ---- one-time: weights -> f16 pairs in LDS / registers ----
    float win[4];
#pragma unroll
    for (int r = 0; r < 4; ++r) {
        const int grow = bid * RPB + 4 * rg + r;
#pragma unroll
        for (int c = 0; c < 2; ++c) {
            const float* wr = W_res + (size_t)grow * RES_N + c * 2048 + 8 * cg;
            const float4 a = *(const float4*)wr;
            const float4 b = *(const float4*)(wr + 4);
            uint4 pk;
            pk.x = pkf16(a.x, a.y);
            pk.y = pkf16(a.z, a.w);
            pk.z = pkf16(b.x, b.y);
            pk.w = pkf16(b.z, b.w);
            ((uint4*)w_lds)[((c * 16 + wid) * 4 + r) * 64 + lane] = pk;
        }
        win[r] = W_in[(size_t)grow * INPUT_N + cg];
        PIN(win[r]);
    }
    unsigned wo[8];
#pragma unroll
    for (int m = 0; m < 8; ++m) {
        const int col = (m < 4) ? (8 * cg + 2 * m) : (2048 + 8 * cg + 2 * (m - 4));
        wo[m] = pkf16(W_out[(size_t)bid * RES_N + col],
                      W_out[(size_t)bid * RES_N + col + 1]);
        PIN(wo[m]);
    }

    // This lane's quarter-slice offset (4 consecutive state cols).
    const int ofs_base = ((rg < 2) ? (8 * cg) : (2048 + 8 * cg)) + 4 * (rg & 1);

    float xv = X[cg];  // x_0[cg]

#pragma unroll 1
    for (int t = 0; t <= T_STEPS; ++t) {
        const int par  = t & 1;
        const int ppar = (t + 1) & 1;

        // ---- weight prefetch: state-independent ds_reads issue BEFORE the
        // spin; their latency hides under the wait. PIN pins them live. ----
        uint4 w[2][4];
#pragma unroll
        for (int c = 0; c < 2; ++c)
#pragma unroll
            for (int r = 0; r < 4; ++r) {
                w[c][r] = ((const uint4*)w_lds)[(((c * 16 + wid) * 4 + r) * 64) + lane];
                PINU4(w[c][r]);
            }

        // ---- acquire 4 tagged dwords of state_{t-1} (s_sleep backoff) ----
        unsigned d0, d1, d2, d3;
        if (t == 0) {
            const float4 q = *(const float4*)(state0 + ofs_base);
            d0 = pkf16(q.x, 0.f);
            d1 = pkf16(q.y, 0.f);
            d2 = pkf16(q.z, 0.f);
            d3 = pkf16(q.w, 0.f);
        } else {
            const unsigned exp = (unsigned)t;  // state_{t-1} tagged t
            const ull* sp = (const ull*)(stbuf + (size_t)ppar * RES_N + ofs_base);
            for (;;) {
                const ull lo = __hip_atomic_load(sp, __ATOMIC_RELAXED,
                                                 __HIP_MEMORY_SCOPE_AGENT);
                const ull hi = __hip_atomic_load(sp + 1, __ATOMIC_RELAXED,
                                                 __HIP_MEMORY_SCOPE_AGENT);
                d0 = (unsigned)lo; d1 = (unsigned)(lo >> 32);
                d2 = (unsigned)hi; d3 = (unsigned)(hi >> 32);
                const unsigned tmin =
                    min(min(d0 >> 16, d1 >> 16), min(d2 >> 16, d3 >> 16));
                if (tmin >= exp) break;
                __builtin_amdgcn_s_sleep(1);  // decongest L3 poll traffic
            }
        }

        // prefetch next x (hidden under shuffles/MAC)
        const float xn = X[(size_t)((t + 1 < T_STEPS) ? (t + 1) : 0) * INPUT_N + cg];

        // ---- strip tags into f16x2 pairs, broadcast across the quad ----
        const unsigned pl0 = __builtin_amdgcn_perm(d1, d0, 0x05040100u);
        const unsigned pl1 = __builtin_amdgcn_perm(d3, d2, 0x05040100u);
        unsigned sp16[8];
#pragma unroll
        for (int m = 0; m < 8; ++m)
            sp16[m] = __shfl((m & 1) ? pl1 : pl0, (lane & 0x3C) | (m >> 1), 64);

        // ---- MAC: 4 rows x 8 dot2 on prefetched weights ----
        if (t < T_STEPS) {
            float p0 = win[0] * xv, p1 = win[1] * xv;
            float p2 = win[2] * xv, p3 = win[3] * xv;
#pragma unroll
            for (int c = 0; c < 2; ++c) {
                const unsigned s0 = sp16[4 * c + 0], s1 = sp16[4 * c + 1];
                const unsigned s2 = sp16[4 * c + 2], s3 = sp16[4 * c + 3];
                p0 = fdot2(w[c][0].x, s0, p0); p0 = fdot2(w[c][0].y, s1, p0);
                p0 = fdot2(w[c][0].z, s2, p0); p0 = fdot2(w[c][0].w, s3, p0);
                p1 = fdot2(w[c][1].x, s0, p1); p1 = fdot2(w[c][1].y, s1, p1);
                p1 = fdot2(w[c][1].z, s2, p1); p1 = fdot2(w[c][1].w, s3, p1);
                p2 = fdot2(w[c][2].x, s0, p2); p2 = fdot2(w[c][2].y, s1, p2);
                p2 = fdot2(w[c][2].z, s2, p2); p2 = fdot2(w[c][2].w, s3, p2);
                p3 = fdot2(w[c][3].x, s0, p3); p3 = fdot2(w[c][3].y, s1, p3);
                p3 = fdot2(w[c][3].z, s2, p3); p3 = fdot2(w[c][3].w, s3, p3);
            }
            // merged reduce over the 16 same-rg lanes (stride-4)
            p0 += __shfl_xor(p0, 4, 64); p1 += __shfl_xor(p1, 4, 64);
            p2 += __shfl_xor(p2, 4, 64); p3 += __shfl_xor(p3, 4, 64);
            p0 += __shfl_xor(p0, 8, 64); p1 += __shfl_xor(p1, 8, 64);
            p2 += __shfl_xor(p2, 8, 64); p3 += __shfl_xor(p3, 8, 64);
            float v = (qg & 1) ? ((qg & 2) ? p3 : p1)
                               : ((qg & 2) ? p2 : p0);
            v += __shfl_xor(v, 16, 64);
            v += __shfl_xor(v, 32, 64);
            if (lane < 16)
                lds_part[par][4 * (lane & 3) + (lane >> 2)][wid] = v;  // [row][w]
        }
        __syncthreads();  // the only per-step barrier

        // ---- wave 15: b128 combine + fast_tanh + COALESCED tagged publish ----
        if (t < T_STEPS && wid == 15 && lane < 16) {
            const float4 a = *(const float4*)(&lds_part[par][lane][0]);
            const float4 b = *(const float4*)(&lds_part[par][lane][4]);
            const float4 c = *(const float4*)(&lds_part[par][lane][8]);
            const float4 d = *(const float4*)(&lds_part[par][lane][12]);
            const float s = ((a.x + a.y) + (a.z + a.w)) + ((b.x + b.y) + (b.z + b.w))
                          + ((c.x + c.y) + (c.z + c.w)) + ((d.x + d.y) + (d.z + d.w));
            const float ns = fast_tanh(s);
            const unsigned dw = pkf16(ns, 0.f) | ((unsigned)(t + 1) << 16);
            // 16 lanes, consecutive dwords: one 64B store -> atomic visibility
            __hip_atomic_store(stbuf + (size_t)par * RES_N + bid * RPB + lane,
                               dw, __ATOMIC_RELAXED, __HIP_MEMORY_SCOPE_AGENT);
        }

        // ---- wave 14: delayed pred reduce -> out[t-2] ----
        if (t >= 2 && wid == 14 && lane < 16) {
            float pv = lds_pp[ppar][lane];
            pv += __shfl_xor(pv, 8, 64);
            pv += __shfl_xor(pv, 4, 64);
            pv += __shfl_xor(pv, 2, 64);
            pv += __shfl_xor(pv, 1, 64);
            if (lane == 0) out[(size_t)(t - 2) * OUTPUT_N + bid] = pv;
        }

        // ---- pred partial for state_{t-1} (off critical path) ----
        if (t > 0) {
            float pp = 0.f;
            if (rg == 0) {
#pragma unroll
                for (int m = 0; m < 8; ++m) pp = fdot2(wo[m], sp16[m], pp);
            }
            pp += __shfl_xor(pp, 4, 64);
            pp += __shfl_xor(pp, 8, 64);
            pp += __shfl_xor(pp, 16, 64);
            pp += __shfl_xor(pp, 32, 64);
            if (lane == 0) lds_pp[par][wid] = pp;
        }

        xv = xn;
    }

    // ---- epilogue: out[T-1] from iteration T's pred partials ----
    __syncthreads();
    if (wid == 14 && lane < 16) {
        float pv = lds_pp[T_STEPS & 1][lane];
        pv += __shfl_xor(pv, 8, 64);
        pv += __shfl_xor(pv, 4, 64);
        pv += __shfl_xor(pv, 2, 64);
        pv += __shfl_xor(pv, 1, 64);
        if (lane == 0) out[(size_t)(T_STEPS - 1) * OUTPUT_N + bid] = pv;
    }
}

extern "C" void kernel_launch(void* const* d_in, const int* in_sizes, int n_in,
                              void* d_out, int out_size, void* d_ws, size_t ws_size,
                              hipStream_t stream) {
    const float* X      = (const float*)d_in[0];
    const float* state0 = (const float*)d_in[1];
    const float* W_in   = (const float*)d_in[2];
    const float* W_res  = (const float*)d_in[3];
    const float* W_out  = (const float*)d_in[4];
    float* out = (float*)d_out;

    unsigned* stbuf = (unsigned*)d_ws;  // 2*4096 tagged dwords = 32 KiB

    // Tags must start below any expected value every call (graph replays
    // reuse d_ws without re-poisoning; stale tags would satisfy the spin).
    (void)hipMemsetAsync(stbuf, 0, 2 * RES_N * sizeof(unsigned), stream);

    esn_persistent<<<dim3(NB), dim3(NT), 0, stream>>>(
        X, state0, W_in, W_res, W_out, out, stbuf);
}